// Round 1
// baseline (2573.136 us; speedup 1.0000x reference)
//
#include <hip/hip_runtime.h>

typedef __attribute__((ext_vector_type(8))) short bh8;
typedef __attribute__((ext_vector_type(4))) float f32x4;

#define NB   8
#define NLAY 3
#define LSEQ 2016
#define NH   4
#define DM   256
#define FCN  64
#define MR   (NB*LSEQ)     /* 16128 */
#define SCL  0.0625f       /* 1/sqrt(D)=1/16 per module quirk */
#define SP   2024          /* LDS S pitch (elements), 16B-aligned rows, 2-way-max bank pattern */

__device__ __forceinline__ float b2f(unsigned short u) {
  union { unsigned int i; float f; } c; c.i = ((unsigned int)u) << 16; return c.f;
}
__device__ __forceinline__ unsigned short f2b(float f) {
  union { float f; unsigned int i; } c; c.f = f;
  unsigned int r = c.i + 0x7fffu + ((c.i >> 16) & 1u);  // RNE
  return (unsigned short)(r >> 16);
}

// ---------------- fp32 -> bf16 weight conversion ----------------
__global__ __launch_bounds__(256) void k_f2bf(const float* __restrict__ s,
    unsigned short* __restrict__ d, int n) {
  int i = blockIdx.x * 256 + threadIdx.x;
  if (i < n) d[i] = f2b(s[i]);
}

// ---------------- input embedding: h = x @ in_w + in_b (K=2) ----------------
__global__ __launch_bounds__(256) void k_embed(const float* __restrict__ x,
    const float* __restrict__ w, const float* __restrict__ bias,
    float* __restrict__ h, unsigned short* __restrict__ hb) {
  int m = blockIdx.x, d = threadIdx.x;
  float v = x[m*2] * w[d] + x[m*2+1] * w[DM + d] + bias[d];
  size_t idx = (size_t)m * DM + d;
  h[idx] = v;
  hb[idx] = f2b(v);
}

// ---------------- generic bf16 MFMA GEMM: C = A(MxK) * W(KxN) + bias ----------------
// MODE 0: row-major bf16 out (optional relu)   [FFN1, final o1]
// MODE 1: Q/K scatter to (b,h,l,32) bf16
// MODE 2: V scatter to (b,h,32,l) bf16 (transposed for PV B-fragments)
// MODE 3: fp32 out = acc + bias + res (residual), N==256
template<int MODE, int RELU>
__global__ __launch_bounds__(256) void k_gemm(
    const unsigned short* __restrict__ A, const unsigned short* __restrict__ W,
    const float* __restrict__ bias, const float* __restrict__ res,
    void* __restrict__ outp, int M, int N, int K)
{
  __shared__ unsigned short As[64 * 40];  // (m,k) pitch 40
  __shared__ unsigned short Ws[64 * 40];  // transposed (n,k) pitch 40
  const int t = threadIdx.x;
  const int lane = t & 63, w = t >> 6;
  const int bm = blockIdx.y << 6, bn = blockIdx.x << 6;
  const int mw = (w & 1) << 5, nw = (w >> 1) << 5;
  const int q = lane >> 4, r = lane & 15;
  const int am = t >> 2, akc = (t & 3) << 3;   // A staging: row, col-chunk
  const int wk = t >> 3, wnc = (t & 7) << 3;   // W staging: k-row, n-chunk

  f32x4 zero = {0.f, 0.f, 0.f, 0.f};
  f32x4 acc[2][2] = {{zero, zero}, {zero, zero}};

  for (int k0 = 0; k0 < K; k0 += 32) {
    uint4 av = *(const uint4*)(A + (size_t)(bm + am) * K + k0 + akc);
    *(uint4*)(As + am * 40 + akc) = av;
    union { uint4 u; unsigned short s[8]; } wv;
    wv.u = *(const uint4*)(W + (size_t)(k0 + wk) * N + bn + wnc);
    #pragma unroll
    for (int j = 0; j < 8; ++j) Ws[(wnc + j) * 40 + wk] = wv.s[j];
    __syncthreads();

    bh8 a0 = *(const bh8*)(As + (mw + r) * 40 + (q << 3));
    bh8 a1 = *(const bh8*)(As + (mw + 16 + r) * 40 + (q << 3));
    bh8 b0 = *(const bh8*)(Ws + (nw + r) * 40 + (q << 3));
    bh8 b1 = *(const bh8*)(Ws + (nw + 16 + r) * 40 + (q << 3));
    acc[0][0] = __builtin_amdgcn_mfma_f32_16x16x32_bf16(a0, b0, acc[0][0], 0, 0, 0);
    acc[0][1] = __builtin_amdgcn_mfma_f32_16x16x32_bf16(a0, b1, acc[0][1], 0, 0, 0);
    acc[1][0] = __builtin_amdgcn_mfma_f32_16x16x32_bf16(a1, b0, acc[1][0], 0, 0, 0);
    acc[1][1] = __builtin_amdgcn_mfma_f32_16x16x32_bf16(a1, b1, acc[1][1], 0, 0, 0);
    __syncthreads();
  }

  #pragma unroll
  for (int mi = 0; mi < 2; ++mi)
  #pragma unroll
  for (int ni = 0; ni < 2; ++ni)
  #pragma unroll
  for (int rr = 0; rr < 4; ++rr) {
    int gm = bm + mw + (mi << 4) + (q << 2) + rr;   // C row = quad*4+reg
    int gn = bn + nw + (ni << 4) + r;               // C col = lane&15
    float v = acc[mi][ni][rr] + bias[gn];
    if (RELU) v = v > 0.f ? v : 0.f;
    if (MODE == 0) {
      ((unsigned short*)outp)[(size_t)gm * N + gn] = f2b(v);
    } else if (MODE == 1) {
      int b = gm / LSEQ, l = gm - b * LSEQ;
      int hh = gn >> 5, e = gn & 31;
      ((unsigned short*)outp)[((((size_t)b * NH + hh) * LSEQ + l) << 5) + e] = f2b(v);
    } else if (MODE == 2) {
      int b = gm / LSEQ, l = gm - b * LSEQ;
      int hh = gn >> 5, e = gn & 31;
      ((unsigned short*)outp)[(((size_t)b * NH + hh) * 32 + e) * LSEQ + l] = f2b(v);
    } else {
      size_t idx = (size_t)gm * DM + gn;
      ((float*)outp)[idx] = v + res[idx];
    }
  }
}

// ---------------- residual LayerNorm: wave per row of 256 ----------------
__global__ __launch_bounds__(256) void k_ln(const float* __restrict__ y,
    const float* __restrict__ g, const float* __restrict__ bta,
    float* __restrict__ h, unsigned short* __restrict__ hb)
{
  int t = threadIdx.x, lane = t & 63, w = t >> 6;
  int row = blockIdx.x * 4 + w;
  const float* yr = y + (size_t)row * DM;
  float4 v = *(const float4*)(yr + lane * 4);
  float s = v.x + v.y + v.z + v.w;
  float sq = v.x * v.x + v.y * v.y + v.z * v.z + v.w * v.w;
  #pragma unroll
  for (int m = 1; m < 64; m <<= 1) { s += __shfl_xor(s, m, 64); sq += __shfl_xor(sq, m, 64); }
  float mean = s * (1.f / 256.f);
  float var = sq * (1.f / 256.f) - mean * mean;
  float rs = rsqrtf(var + 1e-5f);
  float4 gg = *(const float4*)(g + lane * 4);
  float4 bb = *(const float4*)(bta + lane * 4);
  float4 o;
  o.x = (v.x - mean) * rs * gg.x + bb.x;
  o.y = (v.y - mean) * rs * gg.y + bb.y;
  o.z = (v.z - mean) * rs * gg.z + bb.z;
  o.w = (v.w - mean) * rs * gg.w + bb.w;
  *(float4*)(h + (size_t)row * DM + lane * 4) = o;
  ushort4 u;
  u.x = f2b(o.x); u.y = f2b(o.y); u.z = f2b(o.z); u.w = f2b(o.w);
  *(ushort4*)(hb + (size_t)row * DM + lane * 4) = u;
}

// ---------------- fused attention: QK^T -> softmax -> P write -> PV ----------------
// block = (b, h, 16 Q-rows); 256 threads (4 waves); S bf16 in LDS (16 x SP)
__global__ __launch_bounds__(256) void k_attn(
    const unsigned short* __restrict__ Qb, const unsigned short* __restrict__ Kb,
    const unsigned short* __restrict__ Vt, float* __restrict__ Pout,
    unsigned short* __restrict__ ao)
{
  __shared__ unsigned short S[16 * SP];
  __shared__ float red[4 * 16 * 32];
  __shared__ float rinv[16];
  const int t = threadIdx.x, lane = t & 63, w = t >> 6;
  const int bid = blockIdx.x;
  const int rb = bid % 126, bh = bid / 126;   // bh = b*NH + h
  const int l0 = rb << 4;
  const int q = lane >> 4, r = lane & 15;

  // phase 1: S = (Q K^T) * SCL, bf16 into LDS
  bh8 qf = *(const bh8*)(Qb + (((size_t)bh * LSEQ + l0 + r) << 5) + (q << 3));
  for (int st = w; st < 126; st += 4) {
    int s0 = st << 4;
    bh8 kf = *(const bh8*)(Kb + (((size_t)bh * LSEQ + s0 + r) << 5) + (q << 3));
    f32x4 c = {0.f, 0.f, 0.f, 0.f};
    c = __builtin_amdgcn_mfma_f32_16x16x32_bf16(qf, kf, c, 0, 0, 0);
    #pragma unroll
    for (int rr = 0; rr < 4; ++rr)
      S[(q * 4 + rr) * SP + s0 + r] = f2b(c[rr] * SCL);
  }
  __syncthreads();

  // phase 2: per-row max & sum of exp; store unnormalized e back to LDS
  {
    int row = t >> 4, c = t & 15;   // 16 threads per row, same 16-lane group of a wave
    float mx = -1e30f;
    for (int col = c; col < LSEQ; col += 16)
      mx = fmaxf(mx, b2f(S[row * SP + col]));
    #pragma unroll
    for (int m = 1; m < 16; m <<= 1) mx = fmaxf(mx, __shfl_xor(mx, m, 64));
    float sum = 0.f;
    for (int col = c; col < LSEQ; col += 16) {
      float e = __expf(b2f(S[row * SP + col]) - mx);
      sum += e;
      S[row * SP + col] = f2b(e);
    }
    #pragma unroll
    for (int m = 1; m < 16; m <<= 1) sum += __shfl_xor(sum, m, 64);
    if (c == 0) rinv[row] = 1.f / sum;
  }
  __syncthreads();

  // phase 3: coalesced fp32 P write to d_out
  float* prow0 = Pout + (size_t)bh * LSEQ * LSEQ + (size_t)l0 * LSEQ;
  for (int row = 0; row < 16; ++row) {
    float iv = rinv[row];
    float* pr = prow0 + (size_t)row * LSEQ;
    for (int col = t; col < LSEQ; col += 256)
      pr[col] = b2f(S[row * SP + col]) * iv;
  }

  // phase 4: O = (e @ V) * rinv via MFMA; A = e from LDS, B = Vt (b,h,d,s)
  f32x4 o0 = {0.f, 0.f, 0.f, 0.f}, o1 = {0.f, 0.f, 0.f, 0.f};
  const unsigned short* vtb = Vt + (size_t)bh * 32 * LSEQ;
  for (int st = w; st < 63; st += 4) {
    int s0 = st << 5;
    bh8 pf = *(const bh8*)(S + r * SP + s0 + (q << 3));
    bh8 v0 = *(const bh8*)(vtb + (size_t)r * LSEQ + s0 + (q << 3));
    bh8 v1 = *(const bh8*)(vtb + (size_t)(16 + r) * LSEQ + s0 + (q << 3));
    o0 = __builtin_amdgcn_mfma_f32_16x16x32_bf16(pf, v0, o0, 0, 0, 0);
    o1 = __builtin_amdgcn_mfma_f32_16x16x32_bf16(pf, v1, o1, 0, 0, 0);
  }
  float* rw = red + w * 512;
  #pragma unroll
  for (int rr = 0; rr < 4; ++rr) {
    rw[(q * 4 + rr) * 32 + r] = o0[rr];
    rw[(q * 4 + rr) * 32 + 16 + r] = o1[rr];
  }
  __syncthreads();
  for (int idx = t; idx < 512; idx += 256) {
    int row = idx >> 5, d = idx & 31;
    float v = red[idx] + red[512 + idx] + red[1024 + idx] + red[1536 + idx];
    v *= rinv[row];
    int b = bh >> 2, hh = bh & 3;
    ao[(size_t)(b * LSEQ + l0 + row) * 128 + (hh << 5) + d] = f2b(v);
  }
}

// ---------------- final head: out = t1 @ o2w + o2b  (N=2) ----------------
__global__ __launch_bounds__(256) void k_head(const unsigned short* __restrict__ t1,
    const float* __restrict__ o2w, const float* __restrict__ o2b,
    float* __restrict__ outp)
{
  int t = threadIdx.x, lane = t & 63, w = t >> 6;
  int row = blockIdx.x * 4 + w;
  union { ushort4 u; unsigned short s[4]; } pk;
  pk.u = *(const ushort4*)(t1 + (size_t)row * DM + lane * 4);
  float a0 = 0.f, a1 = 0.f;
  #pragma unroll
  for (int j = 0; j < 4; ++j) {
    float xv = b2f(pk.s[j]);
    int k = lane * 4 + j;
    a0 += xv * o2w[k * 2];
    a1 += xv * o2w[k * 2 + 1];
  }
  #pragma unroll
  for (int m = 1; m < 64; m <<= 1) { a0 += __shfl_xor(a0, m, 64); a1 += __shfl_xor(a1, m, 64); }
  if (lane == 0) {
    outp[(size_t)row * 2]     = a0 + o2b[0];
    outp[(size_t)row * 2 + 1] = a1 + o2b[1];
  }
}

extern "C" void kernel_launch(void* const* d_in, const int* in_sizes, int n_in,
                              void* d_out, int out_size, void* d_ws, size_t ws_size,
                              hipStream_t stream) {
  const float* x    = (const float*)d_in[0];
  const float* in_w = (const float*)d_in[1];
  const float* in_b = (const float*)d_in[2];
  const float* qw   = (const float*)d_in[3];
  const float* qb   = (const float*)d_in[4];
  const float* kw   = (const float*)d_in[5];
  const float* kb   = (const float*)d_in[6];
  const float* vw   = (const float*)d_in[7];
  const float* vb   = (const float*)d_in[8];
  const float* ow   = (const float*)d_in[9];
  const float* ob   = (const float*)d_in[10];
  const float* f1w  = (const float*)d_in[11];
  const float* f1b  = (const float*)d_in[12];
  const float* f2w  = (const float*)d_in[13];
  const float* f2b  = (const float*)d_in[14];
  const float* n1g  = (const float*)d_in[15];
  const float* n1b  = (const float*)d_in[16];
  const float* n2g  = (const float*)d_in[17];
  const float* n2b  = (const float*)d_in[18];
  const float* o1w  = (const float*)d_in[19];
  const float* o1b  = (const float*)d_in[20];
  const float* o2w  = (const float*)d_in[21];
  const float* o2b  = (const float*)d_in[22];

  char* p = (char*)d_ws;
  auto alloc = [&](size_t bytes) { char* r = p; p += (bytes + 255) & ~(size_t)255; return r; };
  float*          h    = (float*)alloc((size_t)MR * DM * 4);
  unsigned short* hb   = (unsigned short*)alloc((size_t)MR * DM * 2);
  float*          tmp  = (float*)alloc((size_t)MR * DM * 4);
  unsigned short* Qb   = (unsigned short*)alloc((size_t)MR * 128 * 2);
  unsigned short* Kb   = (unsigned short*)alloc((size_t)MR * 128 * 2);
  unsigned short* Vt   = (unsigned short*)alloc((size_t)MR * 128 * 2);
  unsigned short* ao   = (unsigned short*)alloc((size_t)MR * 128 * 2);
  unsigned short* Fb   = (unsigned short*)alloc((size_t)MR * FCN * 2);
  unsigned short* t1   = (unsigned short*)alloc((size_t)MR * DM * 2);
  unsigned short* qwb  = (unsigned short*)alloc(98304 * 2);
  unsigned short* kwb  = (unsigned short*)alloc(98304 * 2);
  unsigned short* vwb  = (unsigned short*)alloc(98304 * 2);
  unsigned short* owb  = (unsigned short*)alloc(98304 * 2);
  unsigned short* f1wb = (unsigned short*)alloc(49152 * 2);
  unsigned short* f2wb = (unsigned short*)alloc(49152 * 2);
  unsigned short* o1wb = (unsigned short*)alloc(65536 * 2);

  k_f2bf<<<(98304 + 255) / 256, 256, 0, stream>>>(qw, qwb, 98304);
  k_f2bf<<<(98304 + 255) / 256, 256, 0, stream>>>(kw, kwb, 98304);
  k_f2bf<<<(98304 + 255) / 256, 256, 0, stream>>>(vw, vwb, 98304);
  k_f2bf<<<(98304 + 255) / 256, 256, 0, stream>>>(ow, owb, 98304);
  k_f2bf<<<(49152 + 255) / 256, 256, 0, stream>>>(f1w, f1wb, 49152);
  k_f2bf<<<(49152 + 255) / 256, 256, 0, stream>>>(f2w, f2wb, 49152);
  k_f2bf<<<(65536 + 255) / 256, 256, 0, stream>>>(o1w, o1wb, 65536);

  k_embed<<<MR, 256, 0, stream>>>(x, in_w, in_b, h, hb);

  float* outp = (float*)d_out;
  for (int i = 0; i < NLAY; ++i) {
    k_gemm<1, 0><<<dim3(2, 252), 256, 0, stream>>>(hb, qwb + i * 32768, qb + i * 128, nullptr, Qb, MR, 128, 256);
    k_gemm<1, 0><<<dim3(2, 252), 256, 0, stream>>>(hb, kwb + i * 32768, kb + i * 128, nullptr, Kb, MR, 128, 256);
    k_gemm<2, 0><<<dim3(2, 252), 256, 0, stream>>>(hb, vwb + i * 32768, vb + i * 128, nullptr, Vt, MR, 128, 256);
    k_attn<<<4032, 256, 0, stream>>>(Qb, Kb, Vt,
        outp + 32256 + (size_t)i * NB * NH * LSEQ * LSEQ, ao);
    k_gemm<3, 0><<<dim3(4, 252), 256, 0, stream>>>(ao, owb + i * 32768, ob + i * 256, h, tmp, MR, 256, 128);
    k_ln<<<MR / 4, 256, 0, stream>>>(tmp, n1g + i * 256, n1b + i * 256, h, hb);
    k_gemm<0, 1><<<dim3(1, 252), 256, 0, stream>>>(hb, f1wb + i * 16384, f1b + i * 64, nullptr, Fb, MR, 64, 256);
    k_gemm<3, 0><<<dim3(4, 252), 256, 0, stream>>>(Fb, f2wb + i * 16384, f2b + i * 256, h, tmp, MR, 256, 64);
    k_ln<<<MR / 4, 256, 0, stream>>>(tmp, n2g + i * 256, n2b + i * 256, h, hb);
  }
  k_gemm<0, 1><<<dim3(4, 252), 256, 0, stream>>>(hb, o1wb, o1b, nullptr, t1, MR, 256, 256);
  k_head<<<MR / 4, 256, 0, stream>>>(t1, o2w, o2b, outp);
}